// Round 13
// baseline (188.094 us; speedup 1.0000x reference)
//
#include <hip/hip_runtime.h>

#define DF 128

typedef __bf16 bf16x8_t __attribute__((ext_vector_type(8)));
typedef float f32x4_t __attribute__((ext_vector_type(4)));
typedef float f32x2_t __attribute__((ext_vector_type(2)));
typedef unsigned short ushort_t;
typedef ushort_t ushort8_t __attribute__((ext_vector_type(8)));

static __device__ __forceinline__ ushort_t f2bf(float f) {
    union { float f; unsigned int u; } v; v.f = f;
    unsigned int r = v.u + 0x7fffu + ((v.u >> 16) & 1u);   // RNE
    return (ushort_t)(r >> 16);
}

// ================= merged prep: conv_dual | k1_coarse_hist | transpose_w =================
__global__ __launch_bounds__(256) void prep_kernel(
    const float* __restrict__ x, ushort_t* __restrict__ Xb,
    unsigned char* __restrict__ Xf8, int n8, int nConv,
    const int* __restrict__ dst, int* __restrict__ C,
    int E, int CH, int NCH, int NBKT,
    const float* __restrict__ W0, const float* __restrict__ W1,
    const float* __restrict__ W2, const float* __restrict__ W3,
    ushort_t* __restrict__ Wt) {
    __shared__ int lcnt[512];
    const int b = blockIdx.x;
    if (b < nConv) {
        int i = b * 256 + threadIdx.x;
        if (i >= n8) return;
        float4 a = ((const float4*)x)[(size_t)i * 2];
        float4 c4 = ((const float4*)x)[(size_t)i * 2 + 1];
        ushort8_t o;
        o[0] = f2bf(a.x); o[1] = f2bf(a.y); o[2] = f2bf(a.z); o[3] = f2bf(a.w);
        o[4] = f2bf(c4.x); o[5] = f2bf(c4.y); o[6] = f2bf(c4.z); o[7] = f2bf(c4.w);
        ((ushort8_t*)Xb)[i] = o;
        int lo = __builtin_amdgcn_cvt_pk_fp8_f32(a.x, a.y, 0, false);
        lo     = __builtin_amdgcn_cvt_pk_fp8_f32(a.z, a.w, lo, true);
        int hi = __builtin_amdgcn_cvt_pk_fp8_f32(c4.x, c4.y, 0, false);
        hi     = __builtin_amdgcn_cvt_pk_fp8_f32(c4.z, c4.w, hi, true);
        ((uint2*)Xf8)[i] = make_uint2((unsigned int)lo, (unsigned int)hi);
    } else if (b < nConv + NCH) {
        const int c = b - nConv;
        for (int k = threadIdx.x; k < NBKT; k += 256) lcnt[k] = 0;
        __syncthreads();
        const int base = c * CH, lim = min(base + CH, E);
        for (int i = base + threadIdx.x; i < lim; i += 256)
            atomicAdd(&lcnt[dst[i] >> 8], 1);
        __syncthreads();
        for (int k = threadIdx.x; k < NBKT; k += 256) C[k * NCH + c] = lcnt[k];
    } else {
        const int tb = b - nConv - NCH;     // 0..255
        int m = tb >> 6;
        const float* W = (m == 0) ? W0 : (m == 1) ? W1 : (m == 2) ? W2 : W3;
        int idx = (tb & 63) * 256 + threadIdx.x;
        int k = idx >> 7, n = idx & 127;
        Wt[m * 16384 + n * 128 + k] = f2bf(W[idx]);
    }
}

// ================= counting-sort CSR build (no global atomics) =================
__global__ __launch_bounds__(512) void k2a_row_scan(
    int* __restrict__ C, int* __restrict__ rowtot, int NCH) {
    __shared__ int sd[512];
    const int b = blockIdx.x, t = threadIdx.x;
    int v = (t < NCH) ? C[b * NCH + t] : 0;
    sd[t] = v; __syncthreads();
    for (int off = 1; off < 512; off <<= 1) {
        int u = (t >= off) ? sd[t - off] : 0;
        __syncthreads();
        sd[t] += u;
        __syncthreads();
    }
    if (t < NCH) C[b * NCH + t] = sd[t] - v;
    if (t == 511) rowtot[b] = sd[511];
}

__global__ __launch_bounds__(512) void k2b_base_scan(
    const int* __restrict__ rowtot, int* __restrict__ rowbase,
    int* __restrict__ rowptr, int NBKT, int N, int E) {
    __shared__ int sd[512];
    const int t = threadIdx.x;
    int v = (t < NBKT) ? rowtot[t] : 0;
    sd[t] = v; __syncthreads();
    for (int off = 1; off < 512; off <<= 1) {
        int u = (t >= off) ? sd[t - off] : 0;
        __syncthreads();
        sd[t] += u;
        __syncthreads();
    }
    if (t < NBKT) rowbase[t] = sd[t] - v;
    if (t == 0) { rowbase[NBKT] = E; rowptr[N] = E; }
}

__global__ __launch_bounds__(256) void k3_bin_scatter(
    const int* __restrict__ src, const int* __restrict__ dst,
    const int* __restrict__ C, const int* __restrict__ rowbase,
    unsigned int* __restrict__ inter, int E, int CH, int NCH, int NBKT) {
    __shared__ int cur[512];
    const int c = blockIdx.x;
    for (int b = threadIdx.x; b < NBKT; b += 256)
        cur[b] = rowbase[b] + C[b * NCH + c];
    __syncthreads();
    const int base = c * CH, lim = min(base + CH, E);
    for (int i = base + threadIdx.x; i < lim; i += 256) {
        int d = dst[i];
        int s = src[i];
        int pos = atomicAdd(&cur[d >> 8], 1);
        inter[pos] = ((unsigned int)(d & 255) << 24) | (unsigned int)s;
    }
}

#define K4CAP 6144
__global__ __launch_bounds__(256) void k4_fine_scatter(
    const unsigned int* __restrict__ inter, const int* __restrict__ rowbase,
    int* __restrict__ edge_src, int* __restrict__ rowptr, int N) {
    __shared__ unsigned int stage[K4CAP];
    __shared__ unsigned int outv[K4CAP];
    __shared__ int lcnt[256], lofs[256], lrun[256];
    const int b = blockIdx.x, t = threadIdx.x;
    const int base = rowbase[b], count = rowbase[b + 1] - base;
    const int n0 = b << 8;
    const int nn = min(256, N - n0);

    lcnt[t] = 0; lrun[t] = 0;
    __syncthreads();

    if (count <= K4CAP) {
        for (int i = t; i < count; i += 256) {
            unsigned int v = inter[base + i];
            stage[i] = v;
            atomicAdd(&lcnt[v >> 24], 1);
        }
        __syncthreads();
        int cv = lcnt[t];
        lofs[t] = cv; __syncthreads();
        for (int off = 1; off < 256; off <<= 1) {
            int u = (t >= off) ? lofs[t - off] : 0;
            __syncthreads();
            lofs[t] += u;
            __syncthreads();
        }
        lofs[t] -= cv;
        if (t < nn) rowptr[n0 + t] = base + lofs[t];
        __syncthreads();
        for (int i = t; i < count; i += 256) {
            unsigned int v = stage[i];
            int dl = v >> 24;
            int p = lofs[dl] + atomicAdd(&lrun[dl], 1);
            outv[p] = v & 0xFFFFFFu;
        }
        __syncthreads();
        for (int i = t; i < count; i += 256) edge_src[base + i] = (int)outv[i];
    } else {
        for (int i = t; i < count; i += 256)
            atomicAdd(&lcnt[inter[base + i] >> 24], 1);
        __syncthreads();
        int cv = lcnt[t];
        lofs[t] = cv; __syncthreads();
        for (int off = 1; off < 256; off <<= 1) {
            int u = (t >= off) ? lofs[t - off] : 0;
            __syncthreads();
            lofs[t] += u;
            __syncthreads();
        }
        lofs[t] -= cv;
        if (t < nn) rowptr[n0 + t] = base + lofs[t];
        __syncthreads();
        for (int i = t; i < count; i += 256) {
            unsigned int v = inter[base + i];
            int dl = v >> 24;
            int p = atomicAdd(&lrun[dl], 1);
            edge_src[base + lofs[dl] + p] = (int)(v & 0xFFFFFFu);
        }
    }
}

// ---------------- mean aggregation over fp8 rows (R9 verbatim — local optimum) ----------------
// Shape verdict after R8/R10/R11: 16 lanes/edge x uint2, 4 edges/group, idx
// preload + full-wave clamped shfl broadcast. Do not touch without new evidence.
__global__ __launch_bounds__(256, 4) void aggregate_fp8_kernel(
    const unsigned char* __restrict__ Xf8, const int* __restrict__ rowptr,
    const int* __restrict__ edge_src, ushort_t* __restrict__ out, int N) {
    int node = (int)((blockIdx.x * 256u + threadIdx.x) >> 6);
    int lane = threadIdx.x & 63;
    if (node >= N) return;
    const int g = lane >> 4;
    const int s = lane & 15;
    int beg = rowptr[node], end = rowptr[node + 1];
    int deg = end - beg;
    f32x2_t ac0 = {0.f, 0.f}, ac1 = {0.f, 0.f}, ac2 = {0.f, 0.f}, ac3 = {0.f, 0.f};
    for (int b0 = 0; b0 < deg; b0 += 64) {
        int nb = min(64, deg - b0);
        int idx = (lane < nb) ? edge_src[beg + b0 + lane] : 0;
        int nfull = nb >> 4;                  // full 16-edge rounds (uniform)
        for (int it = 0; it < nfull; ++it) {
            int j = it * 16 + g * 4;          // group g owns edges j..j+3
            int s0 = __shfl(idx, j, 64);
            int s1 = __shfl(idx, j + 1, 64);
            int s2 = __shfl(idx, j + 2, 64);
            int s3 = __shfl(idx, j + 3, 64);
            uint2 v0 = *(const uint2*)(Xf8 + (size_t)s0 * DF + s * 8);
            uint2 v1 = *(const uint2*)(Xf8 + (size_t)s1 * DF + s * 8);
            uint2 v2 = *(const uint2*)(Xf8 + (size_t)s2 * DF + s * 8);
            uint2 v3 = *(const uint2*)(Xf8 + (size_t)s3 * DF + s * 8);
            ac0 += __builtin_amdgcn_cvt_pk_f32_fp8((int)v0.x, false);
            ac1 += __builtin_amdgcn_cvt_pk_f32_fp8((int)v0.x, true);
            ac2 += __builtin_amdgcn_cvt_pk_f32_fp8((int)v0.y, false);
            ac3 += __builtin_amdgcn_cvt_pk_f32_fp8((int)v0.y, true);
            ac0 += __builtin_amdgcn_cvt_pk_f32_fp8((int)v1.x, false);
            ac1 += __builtin_amdgcn_cvt_pk_f32_fp8((int)v1.x, true);
            ac2 += __builtin_amdgcn_cvt_pk_f32_fp8((int)v1.y, false);
            ac3 += __builtin_amdgcn_cvt_pk_f32_fp8((int)v1.y, true);
            ac0 += __builtin_amdgcn_cvt_pk_f32_fp8((int)v2.x, false);
            ac1 += __builtin_amdgcn_cvt_pk_f32_fp8((int)v2.x, true);
            ac2 += __builtin_amdgcn_cvt_pk_f32_fp8((int)v2.y, false);
            ac3 += __builtin_amdgcn_cvt_pk_f32_fp8((int)v2.y, true);
            ac0 += __builtin_amdgcn_cvt_pk_f32_fp8((int)v3.x, false);
            ac1 += __builtin_amdgcn_cvt_pk_f32_fp8((int)v3.x, true);
            ac2 += __builtin_amdgcn_cvt_pk_f32_fp8((int)v3.y, false);
            ac3 += __builtin_amdgcn_cvt_pk_f32_fp8((int)v3.y, true);
        }
        if (nb & 15) {   // one wave-uniform predicated tail round (<=15 edges)
            int j = nfull * 16 + g * 4;
            int j0 = j, j1 = j + 1, j2 = j + 2, j3 = j + 3;
            int s0 = __shfl(idx, (j0 < nb) ? j0 : 0, 64);   // full wave active
            int s1 = __shfl(idx, (j1 < nb) ? j1 : 0, 64);
            int s2 = __shfl(idx, (j2 < nb) ? j2 : 0, 64);
            int s3 = __shfl(idx, (j3 < nb) ? j3 : 0, 64);
            uint2 z = make_uint2(0, 0);      // fp8 0x00 == 0.0f
            uint2 v0 = z, v1 = z, v2 = z, v3 = z;
            if (j0 < nb) v0 = *(const uint2*)(Xf8 + (size_t)s0 * DF + s * 8);
            if (j1 < nb) v1 = *(const uint2*)(Xf8 + (size_t)s1 * DF + s * 8);
            if (j2 < nb) v2 = *(const uint2*)(Xf8 + (size_t)s2 * DF + s * 8);
            if (j3 < nb) v3 = *(const uint2*)(Xf8 + (size_t)s3 * DF + s * 8);
            ac0 += __builtin_amdgcn_cvt_pk_f32_fp8((int)v0.x, false);
            ac1 += __builtin_amdgcn_cvt_pk_f32_fp8((int)v0.x, true);
            ac2 += __builtin_amdgcn_cvt_pk_f32_fp8((int)v0.y, false);
            ac3 += __builtin_amdgcn_cvt_pk_f32_fp8((int)v0.y, true);
            ac0 += __builtin_amdgcn_cvt_pk_f32_fp8((int)v1.x, false);
            ac1 += __builtin_amdgcn_cvt_pk_f32_fp8((int)v1.x, true);
            ac2 += __builtin_amdgcn_cvt_pk_f32_fp8((int)v1.y, false);
            ac3 += __builtin_amdgcn_cvt_pk_f32_fp8((int)v1.y, true);
            ac0 += __builtin_amdgcn_cvt_pk_f32_fp8((int)v2.x, false);
            ac1 += __builtin_amdgcn_cvt_pk_f32_fp8((int)v2.x, true);
            ac2 += __builtin_amdgcn_cvt_pk_f32_fp8((int)v2.y, false);
            ac3 += __builtin_amdgcn_cvt_pk_f32_fp8((int)v2.y, true);
            ac0 += __builtin_amdgcn_cvt_pk_f32_fp8((int)v3.x, false);
            ac1 += __builtin_amdgcn_cvt_pk_f32_fp8((int)v3.x, true);
            ac2 += __builtin_amdgcn_cvt_pk_f32_fp8((int)v3.y, false);
            ac3 += __builtin_amdgcn_cvt_pk_f32_fp8((int)v3.y, true);
        }
    }
    float r[8] = {ac0[0], ac0[1], ac1[0], ac1[1], ac2[0], ac2[1], ac3[0], ac3[1]};
#pragma unroll
    for (int i = 0; i < 8; ++i) {
        r[i] += __shfl_xor(r[i], 16, 64);
        r[i] += __shfl_xor(r[i], 32, 64);
    }
    if (g == 0) {
        float inv = 1.0f / fmaxf((float)deg, 1.0f);
        ushort8_t o;
#pragma unroll
        for (int i = 0; i < 8; ++i) o[i] = f2bf(r[i] * inv);
        *(ushort8_t*)(out + (size_t)node * DF + s * 8) = o;
    }
}

// ---------------- fused SAGE GEMM via MFMA, one W matrix staged at a time ----------------
// R13 change: when BF16OUT==1, the epilogue ALSO emits h1 as fp8 — staged in the
// (now dead) sW LDS as a 128x128 byte tile (XOR-swizzled: col ^= (row&7)<<4),
// then streamed out as full-line dwordx4 stores. Replaces the conv_b2f8 pass.
// (R10's direct byte-store fusion regressed on partial-line writes; this avoids it.)
template <int BF16OUT>
__global__ __launch_bounds__(256, 3) void sage_mfma_kernel(
    const ushort_t* Xb, const ushort_t* __restrict__ Ab,
    const ushort_t* __restrict__ Wts, const ushort_t* __restrict__ Wtn,
    const float* __restrict__ bias, void* outv, unsigned char* __restrict__ out8,
    int M) {
    __shared__ ushort_t sW[16384];   // 32 KB: [row(128)][k(128)] bf16, swizzled

    const int lane = threadIdx.x & 63;
    const int w = threadIdx.x >> 6;
    const int l15 = lane & 15;
    const int g = lane >> 4;
    const int m0 = blockIdx.x * 128 + w * 32;

    int r0 = m0 + l15;      if (r0 >= M) r0 = M - 1;
    int r1 = m0 + 16 + l15; if (r1 >= M) r1 = M - 1;

    // stage Ws (swizzle on write: byte ^= (row&7)<<4)
    for (int u = threadIdx.x; u < 2048; u += 256) {
        int row = u >> 4;
        int kb  = (u & 15) << 4;
        int swz = kb ^ ((row & 7) << 4);
        *(ushort8_t*)((char*)sW + row * 256 + swz) =
            *(const ushort8_t*)(Wts + ((size_t)row << 7) + (kb >> 1));
    }

    // preload ALL A fragments (both matrices) — overlaps W staging latency
    bf16x8_t a[2][2][4];
#pragma unroll
    for (int mat = 0; mat < 2; ++mat) {
        const ushort_t* As = mat ? Ab : Xb;
#pragma unroll
        for (int ks = 0; ks < 4; ++ks) {
            const int ko = ks * 32 + g * 8;
            a[mat][0][ks] = *(const bf16x8_t*)(As + (size_t)r0 * DF + ko);
            a[mat][1][ks] = *(const bf16x8_t*)(As + (size_t)r1 * DF + ko);
        }
    }

    f32x4_t acc[2][8];
#pragma unroll
    for (int rf = 0; rf < 2; ++rf)
#pragma unroll
        for (int c = 0; c < 8; ++c) acc[rf][c] = (f32x4_t){0.f, 0.f, 0.f, 0.f};

    __syncthreads();
    // MFMA over mat 0 (Ws in LDS)
#pragma unroll
    for (int ks = 0; ks < 4; ++ks) {
        const int kb = ks * 64 + g * 16;
#pragma unroll
        for (int c = 0; c < 8; ++c) {
            int brow = c * 16 + l15;
            bf16x8_t b = *(const bf16x8_t*)((const char*)sW + brow * 256 +
                                            (kb ^ ((brow & 7) << 4)));
            acc[0][c] = __builtin_amdgcn_mfma_f32_16x16x32_bf16(a[0][0][ks], b, acc[0][c], 0, 0, 0);
            acc[1][c] = __builtin_amdgcn_mfma_f32_16x16x32_bf16(a[0][1][ks], b, acc[1][c], 0, 0, 0);
        }
    }
    __syncthreads();   // all waves done reading Ws

    // stage Wn over the same LDS
    for (int u = threadIdx.x; u < 2048; u += 256) {
        int row = u >> 4;
        int kb  = (u & 15) << 4;
        int swz = kb ^ ((row & 7) << 4);
        *(ushort8_t*)((char*)sW + row * 256 + swz) =
            *(const ushort8_t*)(Wtn + ((size_t)row << 7) + (kb >> 1));
    }
    __syncthreads();

    // MFMA over mat 1 (Wn in LDS)
#pragma unroll
    for (int ks = 0; ks < 4; ++ks) {
        const int kb = ks * 64 + g * 16;
#pragma unroll
        for (int c = 0; c < 8; ++c) {
            int brow = c * 16 + l15;
            bf16x8_t b = *(const bf16x8_t*)((const char*)sW + brow * 256 +
                                            (kb ^ ((brow & 7) << 4)));
            acc[0][c] = __builtin_amdgcn_mfma_f32_16x16x32_bf16(a[1][0][ks], b, acc[0][c], 0, 0, 0);
            acc[1][c] = __builtin_amdgcn_mfma_f32_16x16x32_bf16(a[1][1][ks], b, acc[1][c], 0, 0, 0);
        }
    }

    if (BF16OUT) {
        // epilogue: bf16 h1 store + fp8 tile into LDS (sW is dead after last barrier)
        __syncthreads();   // ensure all waves finished reading sW for MFMA mat1
        unsigned char* tile = (unsigned char*)sW;   // 128 x 128 bytes, swizzled
        const int wrow = w * 32;
#pragma unroll
        for (int c = 0; c < 8; ++c) {
            int col = c * 16 + l15;
            float bv = bias[col];
#pragma unroll
            for (int rf = 0; rf < 2; ++rf)
#pragma unroll
                for (int j = 0; j < 4; ++j) {
                    int rl = wrow + rf * 16 + g * 4 + j;   // local row 0..127
                    int row = blockIdx.x * 128 + rl;
                    float v = fmaxf(acc[rf][c][j] + bv, 0.f);
                    if (row < M) ((ushort_t*)outv)[(size_t)row * DF + col] = f2bf(v);
                    int p8 = __builtin_amdgcn_cvt_pk_fp8_f32(v, v, 0, false);
                    tile[rl * DF + (col ^ ((rl & 7) << 4))] = (unsigned char)(p8 & 0xff);
                }
        }
        __syncthreads();
        // stream fp8 tile out: 256 threads x 64 B of one row, full-line dwordx4
        int rl = threadIdx.x >> 1;
        int half = (threadIdx.x & 1) << 6;     // 0 or 64
        int grow = blockIdx.x * 128 + rl;
        if (grow < M) {
            uint4 o[4];
#pragma unroll
            for (int i = 0; i < 4; ++i) {
                int chunk = (half + i * 16) ^ ((rl & 7) << 4);
                o[i] = *(const uint4*)&tile[rl * DF + chunk];
            }
#pragma unroll
            for (int i = 0; i < 4; ++i)
                *(uint4*)(out8 + (size_t)grow * DF + half + i * 16) = o[i];
        }
    } else {
        if (m0 + 32 <= M) {   // fast path: no per-store bounds checks
#pragma unroll
            for (int c = 0; c < 8; ++c) {
                int col = c * 16 + l15;
                float bv = bias[col];
#pragma unroll
                for (int rf = 0; rf < 2; ++rf)
#pragma unroll
                    for (int j = 0; j < 4; ++j) {
                        int row = m0 + rf * 16 + g * 4 + j;
                        float v = fmaxf(acc[rf][c][j] + bv, 0.f);
                        ((float*)outv)[(size_t)row * DF + col] = v;
                    }
            }
        } else {
#pragma unroll
            for (int c = 0; c < 8; ++c) {
                int col = c * 16 + l15;
                float bv = bias[col];
#pragma unroll
                for (int rf = 0; rf < 2; ++rf)
#pragma unroll
                    for (int j = 0; j < 4; ++j) {
                        int row = m0 + rf * 16 + g * 4 + j;
                        if (row < M)
                            ((float*)outv)[(size_t)row * DF + col] =
                                fmaxf(acc[rf][c][j] + bv, 0.f);
                    }
            }
        }
    }
}

extern "C" void kernel_launch(void* const* d_in, const int* in_sizes, int n_in,
                              void* d_out, int out_size, void* d_ws, size_t ws_size,
                              hipStream_t stream) {
    const int N = in_sizes[0] / DF;   // 100000
    const int E = in_sizes[1];        // 1600000

    const float* x   = (const float*)d_in[0];
    const int*   src = (const int*)d_in[1];
    const int*   dst = (const int*)d_in[2];
    const float* Ws1 = (const float*)d_in[3];
    const float* Wn1 = (const float*)d_in[4];
    const float* b1  = (const float*)d_in[5];
    const float* Ws2 = (const float*)d_in[6];
    const float* Wn2 = (const float*)d_in[7];
    const float* b2  = (const float*)d_in[8];
    float* out = (float*)d_out;

    const int NBKT = (N + 255) >> 8;
    int CH = 4096;
    int NCH = (E + CH - 1) / CH;
    while (NCH > 512) { CH <<= 1; NCH = (E + CH - 1) / CH; }

    // workspace layout (~58.7 MB)
    int* rowptr   = (int*)d_ws;                                  // N+1
    int* rowbase  = rowptr + ((N + 1 + 63) & ~63);               // NBKT+1
    int* rowtot   = rowbase + ((NBKT + 1 + 63) & ~63);           // NBKT
    int* C        = rowtot + ((NBKT + 63) & ~63);                // NBKT*NCH
    ushort_t* Wt  = (ushort_t*)(C + ((NBKT * NCH + 63) & ~63));  // 4*16384 bf16
    int* edge_src = (int*)(Wt + 65536);                          // E (+64 pad)
    ushort_t* Xb  = (ushort_t*)(edge_src + ((E + 64 + 63) & ~63));  // N*128 bf16
    ushort_t* Ab  = Xb + (size_t)N * DF;                         // N*128 bf16
    unsigned int* inter = (unsigned int*)Ab;                     // E u32 (dead before Ab use)

    // fp8 gather operands live in d_out (free until gemm2's final write)
    unsigned char* Xf8  = (unsigned char*)d_out;                 // N*128 fp8
    unsigned char* H1f8 = Xf8 + (size_t)N * DF;                  // N*128 fp8

    const int n8 = N * DF / 8;
    const int nConv = (n8 + 255) / 256;

    prep_kernel<<<nConv + NCH + 256, 256, 0, stream>>>(
        x, Xb, Xf8, n8, nConv, dst, C, E, CH, NCH, NBKT,
        Ws1, Wn1, Ws2, Wn2, Wt);
    k2a_row_scan<<<NBKT, 512, 0, stream>>>(C, rowtot, NCH);
    k2b_base_scan<<<1, 512, 0, stream>>>(rowtot, rowbase, rowptr, NBKT, N, E);
    k3_bin_scatter<<<NCH, 256, 0, stream>>>(src, dst, C, rowbase, inter, E, CH, NCH, NBKT);
    k4_fine_scatter<<<NBKT, 256, 0, stream>>>(inter, rowbase, edge_src, rowptr, N);

    const int aggGrid  = (N + 3) / 4;
    const int gemmGrid = (N + 127) / 128;

    // layer 1: agg(Xf8) -> Ab ; h1 = relu(Xb@Ws1 + Ab@Wn1 + b1), bf16 in-place
    // over Xb AND fp8 to H1f8 via LDS-staged full-line stores (conv pass deleted)
    aggregate_fp8_kernel<<<aggGrid, 256, 0, stream>>>(Xf8, rowptr, edge_src, Ab, N);
    sage_mfma_kernel<1><<<gemmGrid, 256, 0, stream>>>(Xb, Ab, Wt, Wt + 16384, b1,
                                                      (void*)Xb, H1f8, N);
    // layer 2: agg(H1f8) -> Ab ; out = relu(h1@Ws2 + Ab@Wn2 + b2) fp32 to d_out
    aggregate_fp8_kernel<<<aggGrid, 256, 0, stream>>>(H1f8, rowptr, edge_src, Ab, N);
    sage_mfma_kernel<0><<<gemmGrid, 256, 0, stream>>>(Xb, Ab, Wt + 32768, Wt + 49152, b2,
                                                      (void*)out, nullptr, N);
}

// Round 14
// 183.312 us; speedup vs baseline: 1.0261x; 1.0261x over previous
//
#include <hip/hip_runtime.h>

#define DF 128

typedef __bf16 bf16x8_t __attribute__((ext_vector_type(8)));
typedef float f32x4_t __attribute__((ext_vector_type(4)));
typedef float f32x2_t __attribute__((ext_vector_type(2)));
typedef unsigned short ushort_t;
typedef ushort_t ushort8_t __attribute__((ext_vector_type(8)));

static __device__ __forceinline__ ushort_t f2bf(float f) {
    union { float f; unsigned int u; } v; v.f = f;
    unsigned int r = v.u + 0x7fffu + ((v.u >> 16) & 1u);   // RNE
    return (ushort_t)(r >> 16);
}
static __device__ __forceinline__ float bf2f(ushort_t v) {
    union { unsigned int u; float f; } c; c.u = ((unsigned int)v) << 16; return c.f;
}

// ================= merged prep: conv_dual | k1_coarse_hist | transpose_w =================
__global__ __launch_bounds__(256) void prep_kernel(
    const float* __restrict__ x, ushort_t* __restrict__ Xb,
    unsigned char* __restrict__ Xf8, int n8, int nConv,
    const int* __restrict__ dst, int* __restrict__ C,
    int E, int CH, int NCH, int NBKT,
    const float* __restrict__ W0, const float* __restrict__ W1,
    const float* __restrict__ W2, const float* __restrict__ W3,
    ushort_t* __restrict__ Wt) {
    __shared__ int lcnt[512];
    const int b = blockIdx.x;
    if (b < nConv) {
        int i = b * 256 + threadIdx.x;
        if (i >= n8) return;
        float4 a = ((const float4*)x)[(size_t)i * 2];
        float4 c4 = ((const float4*)x)[(size_t)i * 2 + 1];
        ushort8_t o;
        o[0] = f2bf(a.x); o[1] = f2bf(a.y); o[2] = f2bf(a.z); o[3] = f2bf(a.w);
        o[4] = f2bf(c4.x); o[5] = f2bf(c4.y); o[6] = f2bf(c4.z); o[7] = f2bf(c4.w);
        ((ushort8_t*)Xb)[i] = o;
        int lo = __builtin_amdgcn_cvt_pk_fp8_f32(a.x, a.y, 0, false);
        lo     = __builtin_amdgcn_cvt_pk_fp8_f32(a.z, a.w, lo, true);
        int hi = __builtin_amdgcn_cvt_pk_fp8_f32(c4.x, c4.y, 0, false);
        hi     = __builtin_amdgcn_cvt_pk_fp8_f32(c4.z, c4.w, hi, true);
        ((uint2*)Xf8)[i] = make_uint2((unsigned int)lo, (unsigned int)hi);
    } else if (b < nConv + NCH) {
        const int c = b - nConv;
        for (int k = threadIdx.x; k < NBKT; k += 256) lcnt[k] = 0;
        __syncthreads();
        const int base = c * CH, lim = min(base + CH, E);
        for (int i = base + threadIdx.x; i < lim; i += 256)
            atomicAdd(&lcnt[dst[i] >> 8], 1);
        __syncthreads();
        for (int k = threadIdx.x; k < NBKT; k += 256) C[k * NCH + c] = lcnt[k];
    } else {
        const int tb = b - nConv - NCH;     // 0..255
        int m = tb >> 6;
        const float* W = (m == 0) ? W0 : (m == 1) ? W1 : (m == 2) ? W2 : W3;
        int idx = (tb & 63) * 256 + threadIdx.x;
        int k = idx >> 7, n = idx & 127;
        Wt[m * 16384 + n * 128 + k] = f2bf(W[idx]);
    }
}

// ================= counting-sort CSR build (no global atomics) =================
__global__ __launch_bounds__(512) void k2a_row_scan(
    int* __restrict__ C, int* __restrict__ rowtot, int NCH) {
    __shared__ int sd[512];
    const int b = blockIdx.x, t = threadIdx.x;
    int v = (t < NCH) ? C[b * NCH + t] : 0;
    sd[t] = v; __syncthreads();
    for (int off = 1; off < 512; off <<= 1) {
        int u = (t >= off) ? sd[t - off] : 0;
        __syncthreads();
        sd[t] += u;
        __syncthreads();
    }
    if (t < NCH) C[b * NCH + t] = sd[t] - v;
    if (t == 511) rowtot[b] = sd[511];
}

// k3: binned scatter. R14: k2b's tiny rowtot exclusive-scan is recomputed
// PER BLOCK in LDS (NBKT<=512 elems, ~10 scan steps — cheap); block 0 also
// publishes rowbase + sentinels for k4. Deletes the k2b dispatch entirely.
__global__ __launch_bounds__(512) void k3_bin_scatter(
    const int* __restrict__ src, const int* __restrict__ dst,
    const int* __restrict__ C, const int* __restrict__ rowtot,
    int* __restrict__ rowbase, int* __restrict__ rowptr,
    unsigned int* __restrict__ inter,
    int E, int CH, int NCH, int NBKT, int N) {
    __shared__ int sd[512];
    __shared__ int cur[512];
    const int c = blockIdx.x;
    const int t = threadIdx.x;
    int v = (t < NBKT) ? rowtot[t] : 0;
    sd[t] = v; __syncthreads();
    for (int off = 1; off < 512; off <<= 1) {
        int u = (t >= off) ? sd[t - off] : 0;
        __syncthreads();
        sd[t] += u;
        __syncthreads();
    }
    int base_ex = sd[t] - v;              // exclusive scan (bucket base)
    if (t < NBKT) cur[t] = base_ex + C[t * NCH + c];
    if (c == 0) {
        if (t < NBKT) rowbase[t] = base_ex;
        if (t == 0) { rowbase[NBKT] = E; rowptr[N] = E; }
    }
    __syncthreads();
    const int base = c * CH, lim = min(base + CH, E);
    for (int i = base + t; i < lim; i += 512) {
        int d = dst[i];
        int s = src[i];
        int pos = atomicAdd(&cur[d >> 8], 1);
        inter[pos] = ((unsigned int)(d & 255) << 24) | (unsigned int)s;
    }
}

#define K4CAP 6144
__global__ __launch_bounds__(256) void k4_fine_scatter(
    const unsigned int* __restrict__ inter, const int* __restrict__ rowbase,
    int* __restrict__ edge_src, int* __restrict__ rowptr, int N) {
    __shared__ unsigned int stage[K4CAP];
    __shared__ unsigned int outv[K4CAP];
    __shared__ int lcnt[256], lofs[256], lrun[256];
    const int b = blockIdx.x, t = threadIdx.x;
    const int base = rowbase[b], count = rowbase[b + 1] - base;
    const int n0 = b << 8;
    const int nn = min(256, N - n0);

    lcnt[t] = 0; lrun[t] = 0;
    __syncthreads();

    if (count <= K4CAP) {
        for (int i = t; i < count; i += 256) {
            unsigned int v = inter[base + i];
            stage[i] = v;
            atomicAdd(&lcnt[v >> 24], 1);
        }
        __syncthreads();
        int cv = lcnt[t];
        lofs[t] = cv; __syncthreads();
        for (int off = 1; off < 256; off <<= 1) {
            int u = (t >= off) ? lofs[t - off] : 0;
            __syncthreads();
            lofs[t] += u;
            __syncthreads();
        }
        lofs[t] -= cv;
        if (t < nn) rowptr[n0 + t] = base + lofs[t];
        __syncthreads();
        for (int i = t; i < count; i += 256) {
            unsigned int v = stage[i];
            int dl = v >> 24;
            int p = lofs[dl] + atomicAdd(&lrun[dl], 1);
            outv[p] = v & 0xFFFFFFu;
        }
        __syncthreads();
        for (int i = t; i < count; i += 256) edge_src[base + i] = (int)outv[i];
    } else {
        for (int i = t; i < count; i += 256)
            atomicAdd(&lcnt[inter[base + i] >> 24], 1);
        __syncthreads();
        int cv = lcnt[t];
        lofs[t] = cv; __syncthreads();
        for (int off = 1; off < 256; off <<= 1) {
            int u = (t >= off) ? lofs[t - off] : 0;
            __syncthreads();
            lofs[t] += u;
            __syncthreads();
        }
        lofs[t] -= cv;
        if (t < nn) rowptr[n0 + t] = base + lofs[t];
        __syncthreads();
        for (int i = t; i < count; i += 256) {
            unsigned int v = inter[base + i];
            int dl = v >> 24;
            int p = atomicAdd(&lrun[dl], 1);
            edge_src[base + lofs[dl] + p] = (int)(v & 0xFFFFFFu);
        }
    }
}

// ---------------- h1 (bf16) -> fp8(e4m3) ----------------
// Kept standalone: both fused-epilogue attempts regressed (R10 partial-line
// byte stores; R13 LDS-staged tile). ~7us is the cheap form.
__global__ __launch_bounds__(256) void conv_b2f8_kernel(
    const ushort_t* __restrict__ in, unsigned char* __restrict__ out8, int n8) {
    int i = blockIdx.x * blockDim.x + threadIdx.x;
    if (i >= n8) return;
    ushort8_t v = ((const ushort8_t*)in)[i];
    int lo = __builtin_amdgcn_cvt_pk_fp8_f32(bf2f(v[0]), bf2f(v[1]), 0, false);
    lo     = __builtin_amdgcn_cvt_pk_fp8_f32(bf2f(v[2]), bf2f(v[3]), lo, true);
    int hi = __builtin_amdgcn_cvt_pk_fp8_f32(bf2f(v[4]), bf2f(v[5]), 0, false);
    hi     = __builtin_amdgcn_cvt_pk_fp8_f32(bf2f(v[6]), bf2f(v[7]), hi, true);
    ((uint2*)out8)[i] = make_uint2((unsigned int)lo, (unsigned int)hi);
}

// ---------------- mean aggregation over fp8 rows (R9 verbatim — local optimum) ----------------
// Shape verdict after R8/R10/R11: 16 lanes/edge x uint2, 4 edges/group, idx
// preload + full-wave clamped shfl broadcast. At 3.2M lines/dispatch this runs
// 4.7 TB/s line-granular (75% of achievable) — service floor. Do not touch.
__global__ __launch_bounds__(256, 4) void aggregate_fp8_kernel(
    const unsigned char* __restrict__ Xf8, const int* __restrict__ rowptr,
    const int* __restrict__ edge_src, ushort_t* __restrict__ out, int N) {
    int node = (int)((blockIdx.x * 256u + threadIdx.x) >> 6);
    int lane = threadIdx.x & 63;
    if (node >= N) return;
    const int g = lane >> 4;
    const int s = lane & 15;
    int beg = rowptr[node], end = rowptr[node + 1];
    int deg = end - beg;
    f32x2_t ac0 = {0.f, 0.f}, ac1 = {0.f, 0.f}, ac2 = {0.f, 0.f}, ac3 = {0.f, 0.f};
    for (int b0 = 0; b0 < deg; b0 += 64) {
        int nb = min(64, deg - b0);
        int idx = (lane < nb) ? edge_src[beg + b0 + lane] : 0;
        int nfull = nb >> 4;                  // full 16-edge rounds (uniform)
        for (int it = 0; it < nfull; ++it) {
            int j = it * 16 + g * 4;          // group g owns edges j..j+3
            int s0 = __shfl(idx, j, 64);
            int s1 = __shfl(idx, j + 1, 64);
            int s2 = __shfl(idx, j + 2, 64);
            int s3 = __shfl(idx, j + 3, 64);
            uint2 v0 = *(const uint2*)(Xf8 + (size_t)s0 * DF + s * 8);
            uint2 v1 = *(const uint2*)(Xf8 + (size_t)s1 * DF + s * 8);
            uint2 v2 = *(const uint2*)(Xf8 + (size_t)s2 * DF + s * 8);
            uint2 v3 = *(const uint2*)(Xf8 + (size_t)s3 * DF + s * 8);
            ac0 += __builtin_amdgcn_cvt_pk_f32_fp8((int)v0.x, false);
            ac1 += __builtin_amdgcn_cvt_pk_f32_fp8((int)v0.x, true);
            ac2 += __builtin_amdgcn_cvt_pk_f32_fp8((int)v0.y, false);
            ac3 += __builtin_amdgcn_cvt_pk_f32_fp8((int)v0.y, true);
            ac0 += __builtin_amdgcn_cvt_pk_f32_fp8((int)v1.x, false);
            ac1 += __builtin_amdgcn_cvt_pk_f32_fp8((int)v1.x, true);
            ac2 += __builtin_amdgcn_cvt_pk_f32_fp8((int)v1.y, false);
            ac3 += __builtin_amdgcn_cvt_pk_f32_fp8((int)v1.y, true);
            ac0 += __builtin_amdgcn_cvt_pk_f32_fp8((int)v2.x, false);
            ac1 += __builtin_amdgcn_cvt_pk_f32_fp8((int)v2.x, true);
            ac2 += __builtin_amdgcn_cvt_pk_f32_fp8((int)v2.y, false);
            ac3 += __builtin_amdgcn_cvt_pk_f32_fp8((int)v2.y, true);
            ac0 += __builtin_amdgcn_cvt_pk_f32_fp8((int)v3.x, false);
            ac1 += __builtin_amdgcn_cvt_pk_f32_fp8((int)v3.x, true);
            ac2 += __builtin_amdgcn_cvt_pk_f32_fp8((int)v3.y, false);
            ac3 += __builtin_amdgcn_cvt_pk_f32_fp8((int)v3.y, true);
        }
        if (nb & 15) {   // one wave-uniform predicated tail round (<=15 edges)
            int j = nfull * 16 + g * 4;
            int j0 = j, j1 = j + 1, j2 = j + 2, j3 = j + 3;
            int s0 = __shfl(idx, (j0 < nb) ? j0 : 0, 64);   // full wave active
            int s1 = __shfl(idx, (j1 < nb) ? j1 : 0, 64);
            int s2 = __shfl(idx, (j2 < nb) ? j2 : 0, 64);
            int s3 = __shfl(idx, (j3 < nb) ? j3 : 0, 64);
            uint2 z = make_uint2(0, 0);      // fp8 0x00 == 0.0f
            uint2 v0 = z, v1 = z, v2 = z, v3 = z;
            if (j0 < nb) v0 = *(const uint2*)(Xf8 + (size_t)s0 * DF + s * 8);
            if (j1 < nb) v1 = *(const uint2*)(Xf8 + (size_t)s1 * DF + s * 8);
            if (j2 < nb) v2 = *(const uint2*)(Xf8 + (size_t)s2 * DF + s * 8);
            if (j3 < nb) v3 = *(const uint2*)(Xf8 + (size_t)s3 * DF + s * 8);
            ac0 += __builtin_amdgcn_cvt_pk_f32_fp8((int)v0.x, false);
            ac1 += __builtin_amdgcn_cvt_pk_f32_fp8((int)v0.x, true);
            ac2 += __builtin_amdgcn_cvt_pk_f32_fp8((int)v0.y, false);
            ac3 += __builtin_amdgcn_cvt_pk_f32_fp8((int)v0.y, true);
            ac0 += __builtin_amdgcn_cvt_pk_f32_fp8((int)v1.x, false);
            ac1 += __builtin_amdgcn_cvt_pk_f32_fp8((int)v1.x, true);
            ac2 += __builtin_amdgcn_cvt_pk_f32_fp8((int)v1.y, false);
            ac3 += __builtin_amdgcn_cvt_pk_f32_fp8((int)v1.y, true);
            ac0 += __builtin_amdgcn_cvt_pk_f32_fp8((int)v2.x, false);
            ac1 += __builtin_amdgcn_cvt_pk_f32_fp8((int)v2.x, true);
            ac2 += __builtin_amdgcn_cvt_pk_f32_fp8((int)v2.y, false);
            ac3 += __builtin_amdgcn_cvt_pk_f32_fp8((int)v2.y, true);
            ac0 += __builtin_amdgcn_cvt_pk_f32_fp8((int)v3.x, false);
            ac1 += __builtin_amdgcn_cvt_pk_f32_fp8((int)v3.x, true);
            ac2 += __builtin_amdgcn_cvt_pk_f32_fp8((int)v3.y, false);
            ac3 += __builtin_amdgcn_cvt_pk_f32_fp8((int)v3.y, true);
        }
    }
    float r[8] = {ac0[0], ac0[1], ac1[0], ac1[1], ac2[0], ac2[1], ac3[0], ac3[1]};
#pragma unroll
    for (int i = 0; i < 8; ++i) {
        r[i] += __shfl_xor(r[i], 16, 64);
        r[i] += __shfl_xor(r[i], 32, 64);
    }
    if (g == 0) {
        float inv = 1.0f / fmaxf((float)deg, 1.0f);
        ushort8_t o;
#pragma unroll
        for (int i = 0; i < 8; ++i) o[i] = f2bf(r[i] * inv);
        *(ushort8_t*)(out + (size_t)node * DF + s * 8) = o;
    }
}

// ---------------- fused SAGE GEMM via MFMA, one W matrix staged at a time ----------------
// (R12 verbatim) 32 KB LDS + launch_bounds(256,3); A-frags preloaded to regs.
template <int BF16OUT>
__global__ __launch_bounds__(256, 3) void sage_mfma_kernel(
    const ushort_t* Xb, const ushort_t* __restrict__ Ab,
    const ushort_t* __restrict__ Wts, const ushort_t* __restrict__ Wtn,
    const float* __restrict__ bias, void* outv, int M) {
    __shared__ ushort_t sW[16384];   // 32 KB: [row(128)][k(128)] bf16, swizzled

    const int lane = threadIdx.x & 63;
    const int w = threadIdx.x >> 6;
    const int l15 = lane & 15;
    const int g = lane >> 4;
    const int m0 = blockIdx.x * 128 + w * 32;

    int r0 = m0 + l15;      if (r0 >= M) r0 = M - 1;
    int r1 = m0 + 16 + l15; if (r1 >= M) r1 = M - 1;

    // stage Ws (swizzle on write: byte ^= (row&7)<<4)
    for (int u = threadIdx.x; u < 2048; u += 256) {
        int row = u >> 4;
        int kb  = (u & 15) << 4;
        int swz = kb ^ ((row & 7) << 4);
        *(ushort8_t*)((char*)sW + row * 256 + swz) =
            *(const ushort8_t*)(Wts + ((size_t)row << 7) + (kb >> 1));
    }

    // preload ALL A fragments (both matrices) — overlaps W staging latency
    bf16x8_t a[2][2][4];
#pragma unroll
    for (int mat = 0; mat < 2; ++mat) {
        const ushort_t* As = mat ? Ab : Xb;
#pragma unroll
        for (int ks = 0; ks < 4; ++ks) {
            const int ko = ks * 32 + g * 8;
            a[mat][0][ks] = *(const bf16x8_t*)(As + (size_t)r0 * DF + ko);
            a[mat][1][ks] = *(const bf16x8_t*)(As + (size_t)r1 * DF + ko);
        }
    }

    f32x4_t acc[2][8];
#pragma unroll
    for (int rf = 0; rf < 2; ++rf)
#pragma unroll
        for (int c = 0; c < 8; ++c) acc[rf][c] = (f32x4_t){0.f, 0.f, 0.f, 0.f};

    __syncthreads();
    // MFMA over mat 0 (Ws in LDS)
#pragma unroll
    for (int ks = 0; ks < 4; ++ks) {
        const int kb = ks * 64 + g * 16;
#pragma unroll
        for (int c = 0; c < 8; ++c) {
            int brow = c * 16 + l15;
            bf16x8_t b = *(const bf16x8_t*)((const char*)sW + brow * 256 +
                                            (kb ^ ((brow & 7) << 4)));
            acc[0][c] = __builtin_amdgcn_mfma_f32_16x16x32_bf16(a[0][0][ks], b, acc[0][c], 0, 0, 0);
            acc[1][c] = __builtin_amdgcn_mfma_f32_16x16x32_bf16(a[0][1][ks], b, acc[1][c], 0, 0, 0);
        }
    }
    __syncthreads();   // all waves done reading Ws

    // stage Wn over the same LDS
    for (int u = threadIdx.x; u < 2048; u += 256) {
        int row = u >> 4;
        int kb  = (u & 15) << 4;
        int swz = kb ^ ((row & 7) << 4);
        *(ushort8_t*)((char*)sW + row * 256 + swz) =
            *(const ushort8_t*)(Wtn + ((size_t)row << 7) + (kb >> 1));
    }
    __syncthreads();

    // MFMA over mat 1 (Wn in LDS)
#pragma unroll
    for (int ks = 0; ks < 4; ++ks) {
        const int kb = ks * 64 + g * 16;
#pragma unroll
        for (int c = 0; c < 8; ++c) {
            int brow = c * 16 + l15;
            bf16x8_t b = *(const bf16x8_t*)((const char*)sW + brow * 256 +
                                            (kb ^ ((brow & 7) << 4)));
            acc[0][c] = __builtin_amdgcn_mfma_f32_16x16x32_bf16(a[1][0][ks], b, acc[0][c], 0, 0, 0);
            acc[1][c] = __builtin_amdgcn_mfma_f32_16x16x32_bf16(a[1][1][ks], b, acc[1][c], 0, 0, 0);
        }
    }

    if (m0 + 32 <= M) {   // fast path: no per-store bounds checks
#pragma unroll
        for (int c = 0; c < 8; ++c) {
            int col = c * 16 + l15;
            float bv = bias[col];
#pragma unroll
            for (int rf = 0; rf < 2; ++rf)
#pragma unroll
                for (int j = 0; j < 4; ++j) {
                    int row = m0 + rf * 16 + g * 4 + j;
                    float v = fmaxf(acc[rf][c][j] + bv, 0.f);
                    if (BF16OUT) ((ushort_t*)outv)[(size_t)row * DF + col] = f2bf(v);
                    else         ((float*)outv)[(size_t)row * DF + col] = v;
                }
        }
    } else {
#pragma unroll
        for (int c = 0; c < 8; ++c) {
            int col = c * 16 + l15;
            float bv = bias[col];
#pragma unroll
            for (int rf = 0; rf < 2; ++rf)
#pragma unroll
                for (int j = 0; j < 4; ++j) {
                    int row = m0 + rf * 16 + g * 4 + j;
                    if (row < M) {
                        float v = fmaxf(acc[rf][c][j] + bv, 0.f);
                        if (BF16OUT) ((ushort_t*)outv)[(size_t)row * DF + col] = f2bf(v);
                        else         ((float*)outv)[(size_t)row * DF + col] = v;
                    }
                }
        }
    }
}

extern "C" void kernel_launch(void* const* d_in, const int* in_sizes, int n_in,
                              void* d_out, int out_size, void* d_ws, size_t ws_size,
                              hipStream_t stream) {
    const int N = in_sizes[0] / DF;   // 100000
    const int E = in_sizes[1];        // 1600000

    const float* x   = (const float*)d_in[0];
    const int*   src = (const int*)d_in[1];
    const int*   dst = (const int*)d_in[2];
    const float* Ws1 = (const float*)d_in[3];
    const float* Wn1 = (const float*)d_in[4];
    const float* b1  = (const float*)d_in[5];
    const float* Ws2 = (const float*)d_in[6];
    const float* Wn2 = (const float*)d_in[7];
    const float* b2  = (const float*)d_in[8];
    float* out = (float*)d_out;

    const int NBKT = (N + 255) >> 8;
    int CH = 4096;
    int NCH = (E + CH - 1) / CH;
    while (NCH > 512) { CH <<= 1; NCH = (E + CH - 1) / CH; }

    // workspace layout (~58.7 MB)
    int* rowptr   = (int*)d_ws;                                  // N+1
    int* rowbase  = rowptr + ((N + 1 + 63) & ~63);               // NBKT+1
    int* rowtot   = rowbase + ((NBKT + 1 + 63) & ~63);           // NBKT
    int* C        = rowtot + ((NBKT + 63) & ~63);                // NBKT*NCH
    ushort_t* Wt  = (ushort_t*)(C + ((NBKT * NCH + 63) & ~63));  // 4*16384 bf16
    int* edge_src = (int*)(Wt + 65536);                          // E (+64 pad)
    ushort_t* Xb  = (ushort_t*)(edge_src + ((E + 64 + 63) & ~63));  // N*128 bf16
    ushort_t* Ab  = Xb + (size_t)N * DF;                         // N*128 bf16
    unsigned int* inter = (unsigned int*)Ab;                     // E u32 (dead before Ab use)

    // fp8 gather operands live in d_out (free until gemm2's final write)
    unsigned char* Xf8  = (unsigned char*)d_out;                 // N*128 fp8
    unsigned char* H1f8 = Xf8 + (size_t)N * DF;                  // N*128 fp8

    const int n8 = N * DF / 8;
    const int nConv = (n8 + 255) / 256;

    prep_kernel<<<nConv + NCH + 256, 256, 0, stream>>>(
        x, Xb, Xf8, n8, nConv, dst, C, E, CH, NCH, NBKT,
        Ws1, Wn1, Ws2, Wn2, Wt);
    k2a_row_scan<<<NBKT, 512, 0, stream>>>(C, rowtot, NCH);
    k3_bin_scatter<<<NCH, 512, 0, stream>>>(src, dst, C, rowtot, rowbase, rowptr,
                                            inter, E, CH, NCH, NBKT, N);
    k4_fine_scatter<<<NBKT, 256, 0, stream>>>(inter, rowbase, edge_src, rowptr, N);

    const int aggGrid  = (N + 3) / 4;
    const int gemmGrid = (N + 127) / 128;

    // layer 1: agg(Xf8) -> Ab ; h1 = relu(Xb@Ws1 + Ab@Wn1 + b1) bf16 in-place over Xb
    aggregate_fp8_kernel<<<aggGrid, 256, 0, stream>>>(Xf8, rowptr, edge_src, Ab, N);
    sage_mfma_kernel<1><<<gemmGrid, 256, 0, stream>>>(Xb, Ab, Wt, Wt + 16384, b1, (void*)Xb, N);
    // h1 -> fp8 for the layer-2 gather
    conv_b2f8_kernel<<<(n8 + 255) / 256, 256, 0, stream>>>(Xb, H1f8, n8);
    // layer 2: agg(H1f8) -> Ab ; out = relu(h1@Ws2 + Ab@Wn2 + b2) fp32 to d_out
    aggregate_fp8_kernel<<<aggGrid, 256, 0, stream>>>(H1f8, rowptr, edge_src, Ab, N);
    sage_mfma_kernel<0><<<gemmGrid, 256, 0, stream>>>(Xb, Ab, Wt + 32768, Wt + 49152, b2, (void*)out, N);
}